// Round 3
// baseline (877.813 us; speedup 1.0000x reference)
//
#include <hip/hip_runtime.h>

#define NN 512
#define ND 1024
#define NDW 524288   // N*D
#define NBATCH 64

typedef __attribute__((ext_vector_type(8))) __bf16 bf16x8;
typedef __attribute__((ext_vector_type(4))) float f32x4;
typedef unsigned short u16;
typedef unsigned int u32;

__device__ __forceinline__ u16 f2bf(float x) {
    u32 u = __float_as_uint(x);
    u = (u + 0x7fffu + ((u >> 16) & 1u)) >> 16;   // RNE
    return (u16)u;
}
__device__ __forceinline__ float bf2f(u16 x) {
    return __uint_as_float(((u32)x) << 16);
}

union BF8 { bf16x8 v; u16 s[8]; };

__global__ __launch_bounds__(256)
void nma_init_out(float* __restrict__ out, const float* __restrict__ fcb) {
    int t = threadIdx.x;
    if (t < NBATCH * 4) out[t] = fcb[t & 3];
}

// Ke = bf16(K + emb[eid]) row-major [B,N,D]
__global__ __launch_bounds__(256)
void prep_ke(const float* __restrict__ K, const int* __restrict__ eid,
             const float* __restrict__ emb, u16* __restrict__ Ke) {
    size_t f = ((size_t)blockIdx.x * 256 + threadIdx.x) * 8;
    int n = (int)((f >> 10) & (NN - 1));
    int col = (int)(f & (ND - 1));
    const float* kp = K + f;
    const float* ep = emb + (size_t)eid[n] * ND + col;
    float4 k0 = *(const float4*)kp, k1 = *(const float4*)(kp + 4);
    float4 e0 = *(const float4*)ep, e1 = *(const float4*)(ep + 4);
    union { uint4 q; u16 s[8]; } o;
    o.s[0]=f2bf(k0.x+e0.x); o.s[1]=f2bf(k0.y+e0.y); o.s[2]=f2bf(k0.z+e0.z); o.s[3]=f2bf(k0.w+e0.w);
    o.s[4]=f2bf(k1.x+e1.x); o.s[5]=f2bf(k1.y+e1.y); o.s[6]=f2bf(k1.z+e1.z); o.s[7]=f2bf(k1.w+e1.w);
    *(uint4*)(Ke + f) = o.q;
}

// VT[b,d,n] = bf16(V[b,n,d] + emb[eid[n],d]) — 64x64 LDS tile transpose
__global__ __launch_bounds__(256)
void prep_vt(const float* __restrict__ V, const int* __restrict__ eid,
             const float* __restrict__ emb, u16* __restrict__ VT) {
    __shared__ u16 T[64 * 72];
    const int tid = threadIdx.x;
    const int b = blockIdx.z, d0 = blockIdx.y * 64, n0 = blockIdx.x * 64;
    {
        const int r = tid >> 2, cs = (tid & 3) * 16;
        const int n = n0 + r;
        const float* vp = V + ((size_t)b * NN + n) * ND + d0 + cs;
        const float* ep = emb + (size_t)eid[n] * ND + d0 + cs;
        #pragma unroll
        for (int j = 0; j < 4; ++j) {
            float4 v = *(const float4*)(vp + j * 4);
            float4 e = *(const float4*)(ep + j * 4);
            T[(cs + j*4 + 0) * 72 + r] = f2bf(v.x + e.x);
            T[(cs + j*4 + 1) * 72 + r] = f2bf(v.y + e.y);
            T[(cs + j*4 + 2) * 72 + r] = f2bf(v.z + e.z);
            T[(cs + j*4 + 3) * 72 + r] = f2bf(v.w + e.w);
        }
    }
    __syncthreads();
    {
        const int dr = tid >> 2, ms = (tid & 3) * 16;
        u16* dst = VT + ((size_t)b * ND + d0 + dr) * NN + n0 + ms;
        *(uint4*)dst       = *(const uint4*)&T[dr * 72 + ms];
        *(uint4*)(dst + 8) = *(const uint4*)&T[dr * 72 + ms + 8];
    }
}

// One block per (b, 32-row Q tile). Dead-path: neuromod term is per-row const,
// cancels in (ms-mean)/std -> only QK^T -> z-softmax -> PV survives.
// Barrier-free main loops: B-operand MFMA fragments loaded DIRECTLY from
// global (L1/L2-resident Ke/VT), compiler pipelines with fine-grained vmcnt.
// LDS only for P round-trip + row stats => ~36KB => 4 blocks/CU.
__global__ __launch_bounds__(256, 4)
void nma_attn(const float* __restrict__ Q, const int* __restrict__ eid,
              const float* __restrict__ emb, const u16* __restrict__ Ke,
              const u16* __restrict__ VT, u16* __restrict__ O)
{
    __shared__ __align__(16) u16 Ps[32 * 520];    // probs bf16
    __shared__ float red[4][32][4];
    __shared__ float rowM[32], rowInv[32], rowRden[32];

    const int tid  = threadIdx.x;
    const int w    = tid >> 6;
    const int lane = tid & 63;
    const int q    = lane >> 4;
    const int l15  = lane & 15;
    const int bid  = blockIdx.x;
    const int jj   = bid >> 3;
    const int b    = (bid & 7) + ((jj >> 4) << 3);   // XCD swizzle: batch tiles share an XCD L2
    const int i0   = (jj & 15) * 32;
    const size_t bOff = (size_t)b * NN * ND;

    const float* Qrow0 = Q + bOff + (size_t)(i0 + l15) * ND;
    const float* Qrow1 = Q + bOff + (size_t)(i0 + 16 + l15) * ND;
    const float* Erow0 = emb + (size_t)eid[i0 + l15] * ND;
    const float* Erow1 = emb + (size_t)eid[i0 + 16 + l15] * ND;

    // per-lane fragment base pointers (row = w*128 + l15, k-offset q*8)
    const u16* KeRow = Ke + bOff + (size_t)(w * 128 + l15) * ND + q * 8;
    const u16* VTRow = VT + (size_t)b * ND * NN + (size_t)(w * 128 + l15) * NN + q * 8;

    f32x4 acc[2][8];
    #pragma unroll
    for (int it = 0; it < 2; ++it)
        #pragma unroll
        for (int mt = 0; mt < 8; ++mt)
            acc[it][mt] = (f32x4){0.f, 0.f, 0.f, 0.f};

    // ---- Phase 2: S = Qe * Ke^T  (no barriers) ----
    for (int kc = 0; kc < 32; ++kc) {
        const int k0 = kc * 32 + q * 8;
        bf16x8 bv[8];
        #pragma unroll
        for (int mt = 0; mt < 8; ++mt)
            bv[mt] = *(const bf16x8*)(KeRow + (size_t)mt * 16 * ND + kc * 32);
        BF8 a0u, a1u;
        {
            float4 x0 = *(const float4*)(Qrow0 + k0);
            float4 x1 = *(const float4*)(Qrow0 + k0 + 4);
            float4 e0 = *(const float4*)(Erow0 + k0);
            float4 e1 = *(const float4*)(Erow0 + k0 + 4);
            a0u.s[0] = f2bf(x0.x + e0.x); a0u.s[1] = f2bf(x0.y + e0.y);
            a0u.s[2] = f2bf(x0.z + e0.z); a0u.s[3] = f2bf(x0.w + e0.w);
            a0u.s[4] = f2bf(x1.x + e1.x); a0u.s[5] = f2bf(x1.y + e1.y);
            a0u.s[6] = f2bf(x1.z + e1.z); a0u.s[7] = f2bf(x1.w + e1.w);
            x0 = *(const float4*)(Qrow1 + k0);
            x1 = *(const float4*)(Qrow1 + k0 + 4);
            e0 = *(const float4*)(Erow1 + k0);
            e1 = *(const float4*)(Erow1 + k0 + 4);
            a1u.s[0] = f2bf(x0.x + e0.x); a1u.s[1] = f2bf(x0.y + e0.y);
            a1u.s[2] = f2bf(x0.z + e0.z); a1u.s[3] = f2bf(x0.w + e0.w);
            a1u.s[4] = f2bf(x1.x + e1.x); a1u.s[5] = f2bf(x1.y + e1.y);
            a1u.s[6] = f2bf(x1.z + e1.z); a1u.s[7] = f2bf(x1.w + e1.w);
        }
        #pragma unroll
        for (int mt = 0; mt < 8; ++mt) {
            acc[0][mt] = __builtin_amdgcn_mfma_f32_16x16x32_bf16(a0u.v, bv[mt], acc[0][mt], 0, 0, 0);
            acc[1][mt] = __builtin_amdgcn_mfma_f32_16x16x32_bf16(a1u.v, bv[mt], acc[1][mt], 0, 0, 0);
        }
    }

    // ---- Phase 3: exact row stats (mean, ddof=1 std, max), softmax(z) ----
    const float SC = 0.03125f;
    #pragma unroll
    for (int it = 0; it < 2; ++it)
        #pragma unroll
        for (int mt = 0; mt < 8; ++mt) {
            acc[it][mt][0] *= SC; acc[it][mt][1] *= SC;
            acc[it][mt][2] *= SC; acc[it][mt][3] *= SC;
        }
    float ssum[2][4], ssq[2][4], smax[2][4];
    #pragma unroll
    for (int it = 0; it < 2; ++it)
        #pragma unroll
        for (int r = 0; r < 4; ++r) {
            float s = 0.f, s2 = 0.f, mx = -3.4e38f;
            #pragma unroll
            for (int mt = 0; mt < 8; ++mt) {
                float v = acc[it][mt][r];
                s += v; s2 += v * v; mx = fmaxf(mx, v);
            }
            #pragma unroll
            for (int d = 1; d < 16; d <<= 1) {
                s  += __shfl_xor(s, d);
                s2 += __shfl_xor(s2, d);
                mx  = fmaxf(mx, __shfl_xor(mx, d));
            }
            ssum[it][r] = s; ssq[it][r] = s2; smax[it][r] = mx;
        }
    if (l15 == 0) {
        #pragma unroll
        for (int it = 0; it < 2; ++it)
            #pragma unroll
            for (int r = 0; r < 4; ++r) {
                int i = it * 16 + q * 4 + r;
                red[w][i][0] = ssum[it][r];
                red[w][i][1] = ssq[it][r];
                red[w][i][2] = smax[it][r];
            }
    }
    __syncthreads();
    if (tid < 32) {
        float s  = red[0][tid][0] + red[1][tid][0] + red[2][tid][0] + red[3][tid][0];
        float s2 = red[0][tid][1] + red[1][tid][1] + red[2][tid][1] + red[3][tid][1];
        float mx = fmaxf(fmaxf(red[0][tid][2], red[1][tid][2]),
                         fmaxf(red[2][tid][2], red[3][tid][2]));
        float mu  = s * (1.f / 512.f);
        float var = fmaxf((s2 - s * mu) * (1.f / 511.f), 0.f);
        float sd  = sqrtf(var);
        rowM[tid]   = mx;
        rowInv[tid] = 1.f / (sd + 1e-6f);
    }
    __syncthreads();
    float dsum[2][4];
    #pragma unroll
    for (int it = 0; it < 2; ++it)
        #pragma unroll
        for (int r = 0; r < 4; ++r) {
            int i = it * 16 + q * 4 + r;
            float M = rowM[i], inv = rowInv[i];
            float s = 0.f;
            #pragma unroll
            for (int mt = 0; mt < 8; ++mt) {
                float e = __expf((acc[it][mt][r] - M) * inv);
                acc[it][mt][r] = e; s += e;
            }
            #pragma unroll
            for (int d = 1; d < 16; d <<= 1) s += __shfl_xor(s, d);
            dsum[it][r] = s;
        }
    if (l15 == 0) {
        #pragma unroll
        for (int it = 0; it < 2; ++it)
            #pragma unroll
            for (int r = 0; r < 4; ++r)
                red[w][it * 16 + q * 4 + r][0] = dsum[it][r];
    }
    __syncthreads();
    if (tid < 32)
        rowRden[tid] = 1.f / (red[0][tid][0] + red[1][tid][0] + red[2][tid][0] + red[3][tid][0]);
    __syncthreads();
    #pragma unroll
    for (int it = 0; it < 2; ++it)
        #pragma unroll
        for (int r = 0; r < 4; ++r) {
            int i = it * 16 + q * 4 + r;
            float rd = rowRden[i];
            #pragma unroll
            for (int mt = 0; mt < 8; ++mt) {
                int m = w * 128 + mt * 16 + l15;
                Ps[i * 520 + m] = f2bf(acc[it][mt][r] * rd);
            }
        }
    __syncthreads();   // Ps visible to all waves; last barrier of the kernel

    // ---- Phase 4: O = P * Ve, VT fragments direct from global (no barriers) ----
    for (int h = 0; h < 2; ++h) {
        f32x4 oacc[2][8];
        #pragma unroll
        for (int it = 0; it < 2; ++it)
            #pragma unroll
            for (int dt = 0; dt < 8; ++dt)
                oacc[it][dt] = (f32x4){0.f, 0.f, 0.f, 0.f};
        const u16* VTh = VTRow + (size_t)h * 512 * NN;
        for (int mc = 0; mc < 16; ++mc) {
            bf16x8 bv[8];
            #pragma unroll
            for (int dt = 0; dt < 8; ++dt)
                bv[dt] = *(const bf16x8*)(VTh + (size_t)dt * 16 * NN + mc * 32);
            bf16x8 p0 = *(const bf16x8*)&Ps[l15 * 520 + mc * 32 + q * 8];
            bf16x8 p1 = *(const bf16x8*)&Ps[(16 + l15) * 520 + mc * 32 + q * 8];
            #pragma unroll
            for (int dt = 0; dt < 8; ++dt) {
                oacc[0][dt] = __builtin_amdgcn_mfma_f32_16x16x32_bf16(p0, bv[dt], oacc[0][dt], 0, 0, 0);
                oacc[1][dt] = __builtin_amdgcn_mfma_f32_16x16x32_bf16(p1, bv[dt], oacc[1][dt], 0, 0, 0);
            }
        }
        #pragma unroll
        for (int it = 0; it < 2; ++it)
            #pragma unroll
            for (int dt = 0; dt < 8; ++dt) {
                const int dglob = h * 512 + w * 128 + dt * 16 + l15;
                #pragma unroll
                for (int r = 0; r < 4; ++r) {
                    const int iglob = i0 + it * 16 + q * 4 + r;
                    O[bOff + (size_t)iglob * ND + dglob] = f2bf(oacc[it][dt][r]);
                }
            }
    }
}

// out[b,c] += sum over a 1024-wide slice of O[b,:]*fcw[c,:]; fcw/O streamed once.
__global__ __launch_bounds__(256)
void fc_red(const u16* __restrict__ O, const float* __restrict__ fcw,
            float* __restrict__ out)
{
    __shared__ __align__(16) u16 Osh[64 * 264];
    __shared__ __align__(16) float Fsh[4 * 260];
    const int tid = threadIdx.x;
    const size_t nbase = (size_t)blockIdx.x * 1024;
    const int b = tid >> 2, c = tid & 3;
    float sum = 0.f;
    for (int ch = 0; ch < 4; ++ch) {
        __syncthreads();
        #pragma unroll
        for (int ii = 0; ii < 8; ++ii) {
            int si = ii * 256 + tid;
            int row = si >> 5, col8 = (si & 31) * 8;
            *(uint4*)&Osh[row * 264 + col8] =
                *(const uint4*)(O + (size_t)row * NDW + nbase + ch * 256 + col8);
        }
        {
            int cc = tid >> 6, n4 = (tid & 63) * 4;
            *(float4*)&Fsh[cc * 260 + n4] =
                *(const float4*)(fcw + (size_t)cc * NDW + nbase + ch * 256 + n4);
        }
        __syncthreads();
        #pragma unroll 4
        for (int n8 = 0; n8 < 32; ++n8) {
            union { uint4 v; u16 s[8]; } o4;
            o4.v = *(const uint4*)&Osh[b * 264 + n8 * 8];
            float4 f0 = *(const float4*)&Fsh[c * 260 + n8 * 8];
            float4 f1 = *(const float4*)&Fsh[c * 260 + n8 * 8 + 4];
            sum += bf2f(o4.s[0]) * f0.x + bf2f(o4.s[1]) * f0.y
                 + bf2f(o4.s[2]) * f0.z + bf2f(o4.s[3]) * f0.w
                 + bf2f(o4.s[4]) * f1.x + bf2f(o4.s[5]) * f1.y
                 + bf2f(o4.s[6]) * f1.z + bf2f(o4.s[7]) * f1.w;
        }
    }
    atomicAdd(&out[b * 4 + c], sum);
}

extern "C" void kernel_launch(void* const* d_in, const int* in_sizes, int n_in,
                              void* d_out, int out_size, void* d_ws, size_t ws_size,
                              hipStream_t stream) {
    (void)in_sizes; (void)n_in; (void)ws_size; (void)out_size;
    const float* Q   = (const float*)d_in[0];
    const float* K   = (const float*)d_in[1];
    const float* V   = (const float*)d_in[2];
    const int*   eid = (const int*)d_in[3];
    const float* emb = (const float*)d_in[4];
    const float* fcw = (const float*)d_in[15];
    const float* fcb = (const float*)d_in[16];
    float* out = (float*)d_out;

    u16* Ke = (u16*)d_ws;
    u16* VT = Ke + (size_t)NBATCH * NN * ND;   // +64MB
    u16* O  = VT + (size_t)NBATCH * NN * ND;   // +64MB (total ws use: 192MB)

    nma_init_out<<<dim3(1), dim3(256), 0, stream>>>(out, fcb);
    prep_ke<<<dim3(16384), dim3(256), 0, stream>>>(K, eid, emb, Ke);
    prep_vt<<<dim3(8, 16, 64), dim3(256), 0, stream>>>(V, eid, emb, VT);
    nma_attn<<<dim3(1024), dim3(256), 0, stream>>>(Q, eid, emb, Ke, VT, O);
    fc_red<<<dim3(512), dim3(256), 0, stream>>>(O, fcw, out);
}